// Round 2
// baseline (3619.851 us; speedup 1.0000x reference)
//
#include <hip/hip_runtime.h>
#include <math.h>

#define HID 64
#define UH_LEN 15
#define N_INC 4

#define TWO_PI_365 0.0172142063f
#define TWO_PI_366 0.0171671554f
#define H24_PI     7.63943727f

__device__ __forceinline__ float frcp(float x){ return __builtin_amdgcn_rcpf(x); }
__device__ __forceinline__ float sigf(float x){ return frcp(1.0f + __expf(-x)); }
__device__ __forceinline__ float tanhfast(float x){ return 1.0f - 2.0f*frcp(__expf(2.0f*x)+1.0f); }

// param bound tables (order = PARAM_SPECS)
__device__ const float PLO[30] = {0.5f,0.7f,-2.0f,0.5f,0.05f,0.03f,0.0f,0.1f,0.02f,0.05f,0.0f,
                                  10.0f,5.0f,10.0f,10.0f,5.0f,0.1f,0.001f,0.01f,5.0f,1.0f,0.0f,
                                  0.0f,0.0f,0.0f,0.0f,0.0f,0.0f,1.0f,0.5f};
__device__ const float PHI[30] = {2.0f,1.4f,2.0f,2.0f,0.49f,0.19f,1.0f,1.0f,0.3f,0.5f,0.3f,
                                  300.0f,150.0f,500.0f,1000.0f,400.0f,0.75f,0.05f,0.35f,350.0f,5.0f,0.8f,
                                  0.1f,0.4f,0.2f,0.5f,0.4f,1.0f,6.0f,5.0f};
__device__ const float LOGT[15] = {0.0f,0.69314718f,1.09861229f,1.38629436f,1.60943791f,
                                   1.79175947f,1.94591015f,2.07944154f,2.19722458f,2.30258509f,
                                   2.39789527f,2.48490665f,2.56494936f,2.63905733f,2.70805020f};

__global__ void zero_kernel(float* __restrict__ p, int cnt){
    int i = blockIdx.x*256 + threadIdx.x;
    if (i < cnt) p[i] = 0.0f;
}

// ---------------------------------------------------------------------------
// LSTM parameter net. Block = 256 = 4 waves; each wave owns 4 units.
// No __syncthreads in the t-loop: h4/x4 are per-wave (wave-lockstep LDS order).
// Per-CU LDS traffic now 2048 cyc/t < 2304 cyc/t VALU -> VALU-issue-bound.
// ---------------------------------------------------------------------------
__global__ __launch_bounds__(256, 1) void lstm_kernel(
    const float* __restrict__ x_dyn,    // [N][T][8]
    const float* __restrict__ x_static, // [N][16]
    const float* __restrict__ Wih,      // [256][8]
    const float* __restrict__ Whh,      // [256][64]
    const float* __restrict__ b_lstm,   // [256]
    const float* __restrict__ Ws,       // [64][16]
    const float* __restrict__ bs,       // [64]
    const float* __restrict__ Wout,     // [30][128]
    const float* __restrict__ bout,     // [30]
    float* __restrict__ params,         // [30][N]
    int N, int T, int DSTAT)
{
    __shared__ float4 Wh4[64*64];           // 64 KiB: [j*64+lane] -> gates
    __shared__ float4 Wi4[8*64];            // 8 KiB:  [k*64+lane] -> gates
    __shared__ float4 h4[4][64];            // per-wave h for 4 units
    __shared__ float4 x4[4][8];             // per-wave xt for 4 units

    const int tid = threadIdx.x;
    const int wv = tid >> 6;
    const int ln = tid & 63;
    const int u0 = blockIdx.x*16 + wv*4;    // first of this wave's 4 units

    for (int idx = tid; idx < 64*64; idx += 256) {
        int j = idx >> 6, l = idx & 63;
        float4 w;
        w.x = Whh[( 0*64 + l)*64 + j];
        w.y = Whh[( 1*64 + l)*64 + j];
        w.z = Whh[( 2*64 + l)*64 + j];
        w.w = Whh[( 3*64 + l)*64 + j];
        Wh4[idx] = w;
    }
    for (int idx = tid; idx < 8*64; idx += 256) {
        int k = idx >> 6, l = idx & 63;
        float4 w;
        w.x = Wih[( 0*64 + l)*8 + k];
        w.y = Wih[( 1*64 + l)*8 + k];
        w.z = Wih[( 2*64 + l)*8 + k];
        w.w = Wih[( 3*64 + l)*8 + k];
        Wi4[idx] = w;
    }
    const float b0 = b_lstm[      ln];
    const float b1 = b_lstm[ 64 + ln];
    const float b2 = b_lstm[128 + ln];
    const float b3 = b_lstm[192 + ln];
    h4[wv][ln] = make_float4(0.f,0.f,0.f,0.f);
    float c[4] = {0.f,0.f,0.f,0.f};
    __syncthreads();   // staging done

    int uu[4];
    #pragma unroll
    for (int u = 0; u < 4; ++u) uu[u] = min(u0 + u, N-1);

    for (int t = 0; t < T; ++t) {
        if (ln < 32) {
            int u = ln >> 3, k = ln & 7;
            ((float*)&x4[wv][k])[u] = x_dyn[((size_t)uu[u]*T + t)*8 + k];
        }
        // per-wave LDS; in-order LDS pipe + compiler lgkmcnt -> no barrier
        float a[4][4];
        #pragma unroll
        for (int u = 0; u < 4; ++u) { a[u][0]=b0; a[u][1]=b1; a[u][2]=b2; a[u][3]=b3; }
        #pragma unroll
        for (int k = 0; k < 8; ++k) {
            float4 xv = x4[wv][k];
            float4 w  = Wi4[(k<<6) | ln];
            #pragma unroll
            for (int u = 0; u < 4; ++u) {
                float xu = ((float*)&xv)[u];
                a[u][0]=fmaf(xu,w.x,a[u][0]); a[u][1]=fmaf(xu,w.y,a[u][1]);
                a[u][2]=fmaf(xu,w.z,a[u][2]); a[u][3]=fmaf(xu,w.w,a[u][3]);
            }
        }
        #pragma unroll 16
        for (int j = 0; j < 64; ++j) {
            float4 hv = h4[wv][j];
            float4 w  = Wh4[(j<<6) | ln];
            #pragma unroll
            for (int u = 0; u < 4; ++u) {
                float hu = ((float*)&hv)[u];
                a[u][0]=fmaf(hu,w.x,a[u][0]); a[u][1]=fmaf(hu,w.y,a[u][1]);
                a[u][2]=fmaf(hu,w.z,a[u][2]); a[u][3]=fmaf(hu,w.w,a[u][3]);
            }
        }
        float nh[4];
        #pragma unroll
        for (int u = 0; u < 4; ++u) {
            float ig=sigf(a[u][0]), fg=sigf(a[u][1]), gg=tanhfast(a[u][2]), og=sigf(a[u][3]);
            c[u] = fg*c[u] + ig*gg;
            nh[u] = og*tanhfast(c[u]);
        }
        h4[wv][ln] = make_float4(nh[0], nh[1], nh[2], nh[3]);
    }
    __syncthreads();   // before reusing Wi4 as cross-purpose scratch

    // static encoder: s = tanh(x_static @ Ws.T + bs); scratch in Wi4 space
    float* s_sh = (float*)Wi4;   // [4 waves * 4 units][64] = 1024 floats <= 2048
    {
        const float bsl = bs[ln];
        #pragma unroll
        for (int u = 0; u < 4; ++u) {
            float acc = bsl;
            for (int k = 0; k < DSTAT; ++k)
                acc = fmaf(x_static[(size_t)uu[u]*DSTAT + k], Ws[ln*DSTAT + k], acc);
            s_sh[(wv*4 + u)*64 + ln] = tanhfast(acc);
        }
    }
    // per-wave region writes/reads only -> wave-order suffices (no barrier)

    if (ln < 30) {
        #pragma unroll
        for (int u = 0; u < 4; ++u) {
            int unit = u0 + u;
            if (unit < N) {
                float raw = bout[ln];
                #pragma unroll 8
                for (int m = 0; m < 64; ++m) {
                    float hm = ((const float*)&h4[wv][m])[u];
                    float sm = s_sh[(wv*4 + u)*64 + m];
                    raw = fmaf(hm, Wout[ln*128 + m],      raw);
                    raw = fmaf(sm, Wout[ln*128 + 64 + m], raw);
                }
                float g = sigf(raw);
                params[ln*N + unit] = PLO[ln] + g*(PHI[ln] - PLO[ln]);
            }
        }
    }
}

// ---------------------------------------------------------------------------
// Prep: transpose prcp/tavg/doy to [T][N] and precompute PET (fully parallel).
// ---------------------------------------------------------------------------
__global__ __launch_bounds__(256) void prep_kernel(
    const float* __restrict__ prcp, const float* __restrict__ tavg,
    const int* __restrict__ doy, const float* __restrict__ lat_rad,
    const float* __restrict__ P,     // params, row 0 = HAMON_COEF
    float* __restrict__ petT, float* __restrict__ prT,
    float* __restrict__ taT,  float* __restrict__ dyT, int N, int T)
{
    __shared__ float spr[32][33], sta[32][33], sdy[32][33];
    const int t0 = blockIdx.x*32, nb = blockIdx.y*32;
    const int tx = threadIdx.x, ty = threadIdx.y;
    #pragma unroll
    for (int r = 0; r < 4; ++r) {
        int nl = ty*4 + r, nn = nb + nl, tt = t0 + tx;
        bool ok = (nn < N) && (tt < T);
        size_t idx = (size_t)nn*T + tt;
        spr[nl][tx] = ok ? prcp[idx] : 0.f;
        sta[nl][tx] = ok ? tavg[idx] : 0.f;
        sdy[nl][tx] = ok ? (float)doy[idx] : 1.f;
    }
    __syncthreads();
    const int nn = nb + tx;
    float tanlat = 0.f, HAMON = 0.f;
    if (nn < N) { tanlat = __tanf(lat_rad[nn]); HAMON = P[nn]; }
    #pragma unroll
    for (int r = 0; r < 4; ++r) {
        int tl = ty*4 + r, tt = t0 + tl;
        if (nn < N && tt < T) {
            float pr = spr[tx][tl], ta = sta[tx][tl], dy = sdy[tx][tl];
            float decl  = 0.4093f*__sinf(TWO_PI_365*dy - 1.405f);
            float cosw  = fminf(fmaxf(-tanlat*__tanf(decl), -0.9999f), 0.9999f);
            float daylen= acosf(cosw)*H24_PI;
            float esat  = 0.6108f*__expf(17.27f*ta*frcp(ta + 237.3f));
            float pet   = fmaxf(HAMON*29.8f*daylen*esat*frcp(ta + 273.2f), 0.0f);
            size_t o = (size_t)tt*N + nn;
            petT[o] = pet; prT[o] = pr; taT[o] = ta; dyT[o] = dy;
        }
    }
}

// ---------------------------------------------------------------------------
// Fused physics: Snow17 + SAC-SMA + UH routing + segment atomics.
// 2 units per thread (ILP-2 for the latency-bound serial chain).
// PRE: PET precomputed, inputs transposed [T][N] (coalesced float2 loads).
// ---------------------------------------------------------------------------
template<bool PRE>
__global__ __launch_bounds__(64) void physics_kernel(
    const float* __restrict__ prcp, const float* __restrict__ tavg,
    const int*   __restrict__ doy,  const float* __restrict__ elev_m,
    const float* __restrict__ lat_rad, const float* __restrict__ area_w,
    const int*   __restrict__ basin_idx, const float* __restrict__ P,
    const float* __restrict__ petT, const float* __restrict__ prT,
    const float* __restrict__ taT,  const float* __restrict__ dyT,
    float* __restrict__ out, int N, int T, int B)
{
    const int g  = blockIdx.x*64 + threadIdx.x;
    const int n0 = 2*g;
    if (n0 >= N) return;
    const bool v1 = (n0 + 1) < N;
    int nn[2]; nn[0] = n0; nn[1] = v1 ? n0+1 : n0;

    float SCF[2],PXTEMP[2],MFMAX[2],MFMIN[2],UADJ[2],MBASE[2],TIPM[2],PLWHC[2],NMF[2],DAYGM[2];
    float UZTWM[2],UZFWM[2],LZTWM[2],LZFPM[2],LZFSM[2],UZK[2],LZPK[2],LZSK[2],ZPERC[2],REXP[2];
    float PFREE[2],PCTIM[2],ADIMP[2],SIDE[2],UH_N[2],UH_TAU[2],HAMON[2];
    #pragma unroll
    for (int u = 0; u < 2; ++u) {
        int n = nn[u];
        HAMON[u]=P[0*N+n]; SCF[u]  =P[ 1*N+n]; PXTEMP[u]=P[ 2*N+n]; MFMAX[u]=P[ 3*N+n];
        MFMIN[u]=P[ 4*N+n]; UADJ[u]=P[ 5*N+n]; MBASE[u]=P[ 6*N+n]; TIPM[u] =P[ 7*N+n];
        PLWHC[u]=P[ 8*N+n]; NMF[u] =P[ 9*N+n]; DAYGM[u]=P[10*N+n]; UZTWM[u]=P[11*N+n];
        UZFWM[u]=P[12*N+n]; LZTWM[u]=P[13*N+n]; LZFPM[u]=P[14*N+n]; LZFSM[u]=P[15*N+n];
        UZK[u]  =P[16*N+n]; LZPK[u]=P[17*N+n]; LZSK[u] =P[18*N+n]; ZPERC[u]=P[19*N+n];
        REXP[u] =P[20*N+n]; PFREE[u]=P[21*N+n]; PCTIM[u]=P[22*N+n]; ADIMP[u]=P[23*N+n];
        SIDE[u] =P[25*N+n]; UH_N[u]=P[28*N+n]; UH_TAU[u]=P[29*N+n];
    }

    float pa_fac[2], tanlat[2], wA[2]; int bi[2];
    #pragma unroll
    for (int u = 0; u < 2; ++u) {
        pa_fac[u] = __expf(-elev_m[nn[u]] * (1.0f/8434.0f));
        tanlat[u] = __tanf(lat_rad[nn[u]]);
        wA[u]     = area_w[nn[u]];
        bi[u]     = basin_idx[nn[u]];
    }

    float uh[2][UH_LEN];
    #pragma unroll
    for (int u = 0; u < 2; ++u) {
        float s = 0.f, inv_tau = frcp(UH_TAU[u]);
        #pragma unroll
        for (int l = 0; l < UH_LEN; ++l) {
            uh[u][l] = __expf((UH_N[u]-1.0f)*LOGT[l] - (float)(l+1)*inv_tau);
            s += uh[u][l];
        }
        float is = frcp(s);
        #pragma unroll
        for (int l = 0; l < UH_LEN; ++l) uh[u][l] *= is;
    }

    const float dtq = 1.0f / (float)N_INC;
    float percm[2], lz_max[2], twm_sum[2], inv_uztwm[2], inv_twm[2], inv_uzfwm[2];
    float inv_lzmax[2], inv_side[2], pinc_fac[2];
    #pragma unroll
    for (int u = 0; u < 2; ++u) {
        percm[u]   = LZFPM[u]*LZPK[u] + LZFSM[u]*LZSK[u];
        lz_max[u]  = LZTWM[u] + LZFPM[u] + LZFSM[u];
        twm_sum[u] = UZTWM[u] + LZTWM[u];
        inv_uztwm[u]= frcp(UZTWM[u]); inv_twm[u] = frcp(twm_sum[u]);
        inv_uzfwm[u]= frcp(UZFWM[u]); inv_lzmax[u]= frcp(lz_max[u]);
        inv_side[u] = frcp(1.0f + SIDE[u]);
        pinc_fac[u] = (1.0f - PCTIM[u] - ADIMP[u])*dtq;
    }

    float wi[2]={0.f,0.f}, wq[2]={0.f,0.f}, ati[2]={0.f,0.f};
    float uztwc[2], uzfwc[2], lztwc[2], lzfpc[2], lzfsc[2], adimc[2];
    #pragma unroll
    for (int u = 0; u < 2; ++u) {
        uztwc[u]=0.5f*UZTWM[u]; uzfwc[u]=0.5f*UZFWM[u]; lztwc[u]=0.5f*LZTWM[u];
        lzfpc[u]=0.5f*LZFPM[u]; lzfsc[u]=0.5f*LZFSM[u]; adimc[u]=0.5f*twm_sum[u];
    }
    float hist[2][UH_LEN-1];
    #pragma unroll
    for (int u = 0; u < 2; ++u)
        #pragma unroll
        for (int l = 0; l < UH_LEN-1; ++l) hist[u][l] = 0.f;

    float* q_gauge = out;
    float* q_base  = out + (size_t)B*T;
    float* q_unit  = out + (size_t)2*B*T;

    // current-step inputs (prefetched)
    float prc[2], tac[2], dyc[2], pec[2];
    #define LOAD_STEP(tt, PR, TA, DY, PE) do {                                     \
        if (PRE) {                                                                 \
            size_t base = (size_t)(tt)*N + n0;                                     \
            if (v1) {                                                              \
                float2 p2 = *(const float2*)&prT[base];  PR[0]=p2.x; PR[1]=p2.y;   \
                float2 t2 = *(const float2*)&taT[base];  TA[0]=t2.x; TA[1]=t2.y;   \
                float2 d2 = *(const float2*)&dyT[base];  DY[0]=d2.x; DY[1]=d2.y;   \
                float2 e2 = *(const float2*)&petT[base]; PE[0]=e2.x; PE[1]=e2.y;   \
            } else {                                                               \
                PR[0]=PR[1]=prT[base]; TA[0]=TA[1]=taT[base];                      \
                DY[0]=DY[1]=dyT[base]; PE[0]=PE[1]=petT[base];                     \
            }                                                                      \
        } else {                                                                   \
            _Pragma("unroll")                                                      \
            for (int u = 0; u < 2; ++u) {                                          \
                size_t ix = (size_t)nn[u]*T + (tt);                                \
                PR[u] = prcp[ix]; TA[u] = tavg[ix]; DY[u] = (float)doy[ix];        \
                PE[u] = 0.f;                                                       \
            }                                                                      \
        }                                                                          \
    } while (0)

    LOAD_STEP(0, prc, tac, dyc, pec);

    for (int t = 0; t < T; ++t) {
        float prn[2], tan_[2], dyn_[2], pen[2];
        if (t + 1 < T) LOAD_STEP(t+1, prn, tan_, dyn_, pen);

        float qv[2], bv[2];
        #pragma unroll
        for (int u = 0; u < 2; ++u) {
            const float pr = prc[u], ta = tac[u], dy = dyc[u];
            float pet;
            if (PRE) pet = pec[u];
            else {
                float decl  = 0.4093f*__sinf(TWO_PI_365*dy - 1.405f);
                float cosw  = fminf(fmaxf(-tanlat[u]*__tanf(decl), -0.9999f), 0.9999f);
                float daylen= acosf(cosw)*H24_PI;
                float esat  = 0.6108f*__expf(17.27f*ta*frcp(ta + 237.3f));
                pet = fmaxf(HAMON[u]*29.8f*daylen*esat*frcp(ta + 273.2f), 0.0f);
            }

            // --- Snow17 ---
            bool is_snow = (ta <= PXTEMP[u]);
            float ps    = is_snow ? pr*SCF[u] : 0.0f;
            float prain = is_snow ? 0.0f : pr;
            wi[u] += ps;
            float mf = 0.5f*(MFMAX[u]+MFMIN[u]) + 0.5f*(MFMAX[u]-MFMIN[u])*__sinf(TWO_PI_366*dy);
            ati[u] += TIPM[u]*(fminf(ta, 0.0f) - ati[u]);
            float mros = UADJ[u]*pa_fac[u]*fmaxf(ta,0.0f)*((!is_snow && wi[u]>0.0f)?prain:0.0f)*0.0125f;
            float melt = fminf(fmaxf(mf*fmaxf(ta-MBASE[u],0.0f) + mros - NMF[u]*fmaxf(-ati[u],0.0f), 0.0f), wi[u]);
            wi[u] -= melt;
            float gm = fminf(DAYGM[u], wi[u]);
            wi[u] -= gm;
            float rop   = (wi[u] > 0.0f) ? prain : 0.0f;
            float rfree = prain - rop;
            wq[u] += melt + rop;
            float outq = fmaxf(wq[u] - PLWHC[u]*wi[u], 0.0f);
            wq[u] -= outq;
            float eff = outq + gm + rfree;

            // --- SAC-SMA ---
            float e1 = fminf(pet*uztwc[u]*inv_uztwm[u], uztwc[u]);
            uztwc[u] -= e1;
            float red = pet - e1;
            float e2 = fminf(red, uzfwc[u]);
            uzfwc[u] -= e2; red -= e2;
            float e3 = fminf(red*lztwc[u]*inv_twm[u], lztwc[u]);
            lztwc[u] -= e3;
            float roimp  = eff*PCTIM[u];
            float padimp = eff*ADIMP[u];
            adimc[u] += padimp;
            float ratio = fminf(fmaxf(adimc[u]*inv_twm[u], 0.0f), 1.0f);
            float adsur = padimp*ratio*ratio;
            adimc[u] = fminf(adimc[u] - adsur, twm_sum[u]);
            float surf = roimp + adsur;
            float base = 0.0f;
            float pinc = eff*pinc_fac[u];
            #pragma unroll
            for (int inc = 0; inc < N_INC; ++inc) {
                float bfp = lzfpc[u]*LZPK[u]*dtq;
                float bfs = lzfsc[u]*LZSK[u]*dtq;
                lzfpc[u] -= bfp; lzfsc[u] -= bfs;
                base += (bfp + bfs)*inv_side[u];
                float qif = uzfwc[u]*UZK[u]*dtq;
                uzfwc[u] -= qif; surf += qif;
                float lz_def = (LZTWM[u]-lztwc[u]) + (LZFPM[u]-lzfpc[u]) + (LZFSM[u]-lzfsc[u]);
                float defr = fminf(fmaxf(lz_def*inv_lzmax[u], 1e-6f), 1.0f);
                float perc = percm[u]*(1.0f + ZPERC[u]*__expf(REXP[u]*__logf(defr)))*dtq*uzfwc[u]*inv_uzfwm[u];
                perc = fminf(fminf(perc, uzfwc[u]), fmaxf(lz_def, 0.0f));
                uzfwc[u] -= perc;
                float pfree = perc*PFREE[u];
                lztwc[u] += perc - pfree;
                float ex = fmaxf(lztwc[u] - LZTWM[u], 0.0f);
                lztwc[u] -= ex; pfree += ex;
                float dp  = fmaxf(LZFPM[u] - lzfpc[u], 0.0f);
                float dsx = fmaxf(LZFSM[u] - lzfsc[u], 0.0f);
                float fr  = dp*frcp(fmaxf(dp + dsx, 1e-6f));
                lzfpc[u] += pfree*fr;
                lzfsc[u] += pfree*(1.0f - fr);
                float exq = fmaxf(lzfpc[u] - LZFPM[u], 0.0f);
                lzfpc[u] -= exq; lzfsc[u] += exq;
                float exs = fmaxf(lzfsc[u] - LZFSM[u], 0.0f);
                lzfsc[u] -= exs; surf += exs;
                uztwc[u] += pinc;
                float exu = fmaxf(uztwc[u] - UZTWM[u], 0.0f);
                uztwc[u] -= exu; uzfwc[u] += exu;
                float exf = fmaxf(uzfwc[u] - UZFWM[u], 0.0f);
                uzfwc[u] -= exf; surf += exf;
            }

            // --- routing ---
            float q = uh[u][0]*surf;
            #pragma unroll
            for (int l = 1; l < UH_LEN; ++l) q = fmaf(uh[u][l], hist[u][l-1], q);
            #pragma unroll
            for (int l = UH_LEN-2; l >= 1; --l) hist[u][l] = hist[u][l-1];
            hist[u][0] = surf;
            qv[u] = q + base;
            bv[u] = base;
        }

        q_unit[(size_t)nn[0]*T + t] = qv[0];
        atomicAdd(&q_gauge[(size_t)bi[0]*T + t], qv[0]*wA[0]);
        atomicAdd(&q_base [(size_t)bi[0]*T + t], bv[0]*wA[0]);
        if (v1) {
            q_unit[(size_t)nn[1]*T + t] = qv[1];
            atomicAdd(&q_gauge[(size_t)bi[1]*T + t], qv[1]*wA[1]);
            atomicAdd(&q_base [(size_t)bi[1]*T + t], bv[1]*wA[1]);
        }

        #pragma unroll
        for (int u = 0; u < 2; ++u) { prc[u]=prn[u]; tac[u]=tan_[u]; dyc[u]=dyn_[u]; pec[u]=pen[u]; }
    }
    #undef LOAD_STEP
}

extern "C" void kernel_launch(void* const* d_in, const int* in_sizes, int n_in,
                              void* d_out, int out_size, void* d_ws, size_t ws_size,
                              hipStream_t stream) {
    const float* x_dyn    = (const float*)d_in[0];
    const float* x_static = (const float*)d_in[1];
    const float* prcp     = (const float*)d_in[2];
    const float* tavg     = (const float*)d_in[3];
    const int*   doy      = (const int*)  d_in[4];
    const float* elev_m   = (const float*)d_in[5];
    const float* lat_rad  = (const float*)d_in[6];
    const float* area_w   = (const float*)d_in[7];
    const int*   basin_ix = (const int*)  d_in[8];
    const float* Wih      = (const float*)d_in[10];
    const float* Whh      = (const float*)d_in[11];
    const float* b_lstm   = (const float*)d_in[12];
    const float* Ws       = (const float*)d_in[13];
    const float* bs       = (const float*)d_in[14];
    const float* Wout     = (const float*)d_in[15];
    const float* bout     = (const float*)d_in[16];

    const int N = in_sizes[7];
    const int T = in_sizes[2] / N;
    const int DSTAT = in_sizes[1] / N;
    const int NT = N * T;
    const int B = (out_size - NT) / (2 * T);

    float* params = (float*)d_ws;              // [30][N]
    float* out    = (float*)d_out;

    const size_t per = (size_t)N * T;
    const size_t need_bytes = (30*(size_t)N + 4*per) * sizeof(float);
    const bool pre = (ws_size >= need_bytes);
    float* petT = params + 30*(size_t)N;
    float* prT  = petT + per;
    float* taT  = prT + per;
    float* dyT  = taT + per;

    const int zc = 2 * B * T;
    zero_kernel<<<(zc + 255)/256, 256, 0, stream>>>(out, zc);

    const int blocks_lstm = (N + 15) / 16;     // 16 units/block (4 waves x 4)
    lstm_kernel<<<blocks_lstm, 256, 0, stream>>>(x_dyn, x_static, Wih, Whh, b_lstm,
                                                 Ws, bs, Wout, bout, params, N, T, DSTAT);

    if (pre) {
        dim3 pg((T + 31)/32, (N + 31)/32), pb(32, 8);
        prep_kernel<<<pg, pb, 0, stream>>>(prcp, tavg, doy, lat_rad, params,
                                           petT, prT, taT, dyT, N, T);
    }

    const int npairs = (N + 1) / 2;
    const int pblocks = (npairs + 63) / 64;
    if (pre)
        physics_kernel<true ><<<pblocks, 64, 0, stream>>>(prcp, tavg, doy, elev_m, lat_rad,
                                                          area_w, basin_ix, params,
                                                          petT, prT, taT, dyT, out, N, T, B);
    else
        physics_kernel<false><<<pblocks, 64, 0, stream>>>(prcp, tavg, doy, elev_m, lat_rad,
                                                          area_w, basin_ix, params,
                                                          petT, prT, taT, dyT, out, N, T, B);
}

// Round 3
// 1506.157 us; speedup vs baseline: 2.4034x; 2.4034x over previous
//
#include <hip/hip_runtime.h>
#include <math.h>

#define HID 64
#define UH_LEN 15
#define N_INC 4

#define TWO_PI_365 0.0172142063f
#define TWO_PI_366 0.0171671554f
#define H24_PI     7.63943727f

typedef short short8 __attribute__((ext_vector_type(8)));
typedef float f32x4  __attribute__((ext_vector_type(4)));

__device__ __forceinline__ float frcp(float x){ return __builtin_amdgcn_rcpf(x); }
__device__ __forceinline__ float sigf(float x){ return frcp(1.0f + __expf(-x)); }
__device__ __forceinline__ float tanhfast(float x){ return 1.0f - 2.0f*frcp(__expf(2.0f*x)+1.0f); }

__device__ __forceinline__ unsigned short f2bf(float f){
    unsigned int u = __float_as_uint(f);
    u += 0x7FFF + ((u >> 16) & 1);          // round-to-nearest-even
    return (unsigned short)(u >> 16);
}
__device__ __forceinline__ float bf2f(unsigned short h){
    return __uint_as_float(((unsigned int)h) << 16);
}

// param bound tables (order = PARAM_SPECS)
__device__ const float PLO[30] = {0.5f,0.7f,-2.0f,0.5f,0.05f,0.03f,0.0f,0.1f,0.02f,0.05f,0.0f,
                                  10.0f,5.0f,10.0f,10.0f,5.0f,0.1f,0.001f,0.01f,5.0f,1.0f,0.0f,
                                  0.0f,0.0f,0.0f,0.0f,0.0f,0.0f,1.0f,0.5f};
__device__ const float PHI[30] = {2.0f,1.4f,2.0f,2.0f,0.49f,0.19f,1.0f,1.0f,0.3f,0.5f,0.3f,
                                  300.0f,150.0f,500.0f,1000.0f,400.0f,0.75f,0.05f,0.35f,350.0f,5.0f,0.8f,
                                  0.1f,0.4f,0.2f,0.5f,0.4f,1.0f,6.0f,5.0f};
__device__ const float LOGT[15] = {0.0f,0.69314718f,1.09861229f,1.38629436f,1.60943791f,
                                   1.79175947f,1.94591015f,2.07944154f,2.19722458f,2.30258509f,
                                   2.39789527f,2.48490665f,2.56494936f,2.63905733f,2.70805020f};

__global__ void zero_kernel(float* __restrict__ p, int cnt){
    int i = blockIdx.x*256 + threadIdx.x;
    if (i < cnt) p[i] = 0.0f;
}

// ---------------------------------------------------------------------------
// MFMA LSTM. Block = 256 (4 waves) = 16 units. Wave w computes hidden slice
// j in [16w,16w+16): col-tiles {w,w+4,w+8,w+12} = i,f,g,o.
// Weight B-fragments live in 48 VGPRs (loaded once). h: bf16, double-buffered
// LDS, XOR-swizzled 16B slots. c-state fp32 in registers.
// ---------------------------------------------------------------------------
__global__ __launch_bounds__(256, 1) void lstm_kernel(
    const float* __restrict__ x_dyn,    // [N][T][8]
    const float* __restrict__ x_static, // [N][16]
    const float* __restrict__ Wih,      // [256][8]
    const float* __restrict__ Whh,      // [256][64]
    const float* __restrict__ b_lstm,   // [256]
    const float* __restrict__ Ws,       // [64][16]
    const float* __restrict__ bs,       // [64]
    const float* __restrict__ Wout,     // [30][128]
    const float* __restrict__ bout,     // [30]
    float* __restrict__ params,         // [30][N]
    int N, int T, int DSTAT)
{
    __shared__ unsigned short h_lds[2][16*64];  // 4 KiB, swizzled
    __shared__ float s_sh[16*64];               // head scratch

    const int tid = threadIdx.x;
    const int wv  = tid >> 6;
    const int ln  = tid & 63;
    const int q   = ln >> 4;      // quarter-wave
    const int r16 = ln & 15;
    const int u0  = blockIdx.x * 16;

    // ---- load weight B-fragments into registers ----
    // B[k][n]: k<64 -> Whh[n][k]; 64<=k<72 -> Wih[n][k-64]; else 0.
    // frag elem e: k = 32*kb + 8*q + e; col n = 64*g + 16*wv + r16.
    short8 wf[4][3];
    float  bias[4];
    #pragma unroll
    for (int g = 0; g < 4; ++g) {
        const int n = 64*g + 16*wv + r16;
        bias[g] = b_lstm[n];
        #pragma unroll
        for (int kb = 0; kb < 3; ++kb) {
            short8 w;
            #pragma unroll
            for (int e = 0; e < 8; ++e) {
                int k = 32*kb + 8*q + e;
                float v = 0.0f;
                if (k < 64)      v = Whh[n*64 + k];
                else if (k < 72) v = Wih[n*8 + (k - 64)];
                w[e] = (short)f2bf(v);
            }
            wf[g][kb] = w;
        }
    }

    // zero h buffers
    for (int i = tid; i < 2*16*64; i += 256) ((unsigned short*)h_lds)[i] = 0;
    __syncthreads();

    float c[4] = {0.f, 0.f, 0.f, 0.f};

    // x prefetch (lanes q==0: unit = u0 + r16)
    const int ux = min(u0 + r16, N-1);
    float xf[8];
    if (q == 0) {
        const float* p = x_dyn + ((size_t)ux * T) * 8;
        #pragma unroll
        for (int e = 0; e < 8; ++e) xf[e] = p[e];
    }

    const int jj   = 16*wv + r16;            // this lane's hidden index (write)
    const int swz0 = (q       ^ (r16 & 7)) << 3;
    const int swz1 = ((q + 4) ^ (r16 & 7)) << 3;

    for (int t = 0; t < T; ++t) {
        // A-frag kb2 from x (lanes q==0 hold x[u][0..7], others zero)
        short8 a2;
        #pragma unroll
        for (int e = 0; e < 8; ++e) a2[e] = (q == 0) ? (short)f2bf(xf[e]) : (short)0;

        const int rb = t & 1;
        short8 a0 = *(const short8*)&h_lds[rb][r16*64 + swz0];
        short8 a1 = *(const short8*)&h_lds[rb][r16*64 + swz1];

        // prefetch next x while MFMAs run
        if (q == 0 && t + 1 < T) {
            const float* p = x_dyn + ((size_t)ux * T + (t+1)) * 8;
            #pragma unroll
            for (int e = 0; e < 8; ++e) xf[e] = p[e];
        }

        f32x4 acc[4];
        #pragma unroll
        for (int g = 0; g < 4; ++g) {
            f32x4 a; a[0]=bias[g]; a[1]=bias[g]; a[2]=bias[g]; a[3]=bias[g];
            a = __builtin_amdgcn_mfma_f32_16x16x32_bf16(a0, wf[g][0], a, 0, 0, 0);
            a = __builtin_amdgcn_mfma_f32_16x16x32_bf16(a1, wf[g][1], a, 0, 0, 0);
            a = __builtin_amdgcn_mfma_f32_16x16x32_bf16(a2, wf[g][2], a, 0, 0, 0);
            acc[g] = a;
        }

        const int wb = rb ^ 1;
        #pragma unroll
        for (int r = 0; r < 4; ++r) {
            float iv = sigf(acc[0][r]);
            float fv = sigf(acc[1][r]);
            float gv = tanhfast(acc[2][r]);
            float ov = sigf(acc[3][r]);
            c[r] = fv*c[r] + iv*gv;
            float hv = ov*tanhfast(c[r]);
            int u = 4*q + r;
            h_lds[wb][u*64 + (((jj>>3) ^ (u&7))<<3) + (jj&7)] = f2bf(hv);
        }
        __syncthreads();
    }

    // ---- head ----
    const int fb = T & 1;
    // static encoder: wave wv handles units ul = wv*4 .. wv*4+3
    for (int uu = 0; uu < 4; ++uu) {
        int ul = wv*4 + uu;
        int u  = min(u0 + ul, N-1);
        float a = bs[ln];
        for (int k = 0; k < DSTAT; ++k)
            a = fmaf(x_static[(size_t)u*DSTAT + k], Ws[ln*DSTAT + k], a);
        s_sh[ul*64 + ln] = tanhfast(a);
    }
    // per-wave write/read of its own s-rows -> wave-lockstep order suffices
    if (ln < 30) {
        for (int uu = 0; uu < 4; ++uu) {
            int ul = wv*4 + uu;
            int unit = u0 + ul;
            if (unit < N) {
                float raw = bout[ln];
                #pragma unroll 8
                for (int m = 0; m < 64; ++m) {
                    float hm = bf2f(h_lds[fb][ul*64 + (((m>>3) ^ (ul&7))<<3) + (m&7)]);
                    float sm = s_sh[ul*64 + m];
                    raw = fmaf(hm, Wout[ln*128 + m],      raw);
                    raw = fmaf(sm, Wout[ln*128 + 64 + m], raw);
                }
                float g = sigf(raw);
                params[ln*N + unit] = PLO[ln] + g*(PHI[ln] - PLO[ln]);
            }
        }
    }
}

// ---------------------------------------------------------------------------
// PET precompute (fully parallel, [N][T] layout — same as inputs).
// ---------------------------------------------------------------------------
__global__ __launch_bounds__(256) void pet_kernel(
    const float* __restrict__ tavg, const int* __restrict__ doy,
    const float* __restrict__ lat_rad, const float* __restrict__ P,
    float* __restrict__ pet, int N, int T)
{
    const int n = blockIdx.y;
    const int t = blockIdx.x*256 + threadIdx.x;
    if (t >= T) return;
    const float ta = tavg[(size_t)n*T + t];
    const float dy = (float)doy[(size_t)n*T + t];
    const float tanlat = __tanf(lat_rad[n]);
    const float HAMON  = P[n];
    float decl  = 0.4093f*__sinf(TWO_PI_365*dy - 1.405f);
    float cosw  = fminf(fmaxf(-tanlat*__tanf(decl), -0.9999f), 0.9999f);
    float daylen= acosf(cosw)*H24_PI;
    float esat  = 0.6108f*__expf(17.27f*ta*frcp(ta + 237.3f));
    pet[(size_t)n*T + t] = fmaxf(HAMON*29.8f*daylen*esat*frcp(ta + 273.2f), 0.0f);
}

// ---------------------------------------------------------------------------
// Fused physics (r1 structure: 1 unit/thread, [N][T] loads).
// PETPRE: PET from precomputed array; melt-factor sine from LDS LUT.
// ---------------------------------------------------------------------------
template<bool PETPRE>
__global__ __launch_bounds__(64, 1) void physics_kernel(
    const float* __restrict__ prcp, const float* __restrict__ tavg,
    const int*   __restrict__ doy,  const float* __restrict__ elev_m,
    const float* __restrict__ lat_rad, const float* __restrict__ area_w,
    const int*   __restrict__ basin_idx, const float* __restrict__ P,
    const float* __restrict__ petA,
    float* __restrict__ out, int N, int T, int B)
{
    __shared__ float s366[368];
    for (int i = threadIdx.x; i < 368; i += 64) s366[i] = __sinf(TWO_PI_366 * (float)i);
    __syncthreads();

    int n = blockIdx.x*64 + threadIdx.x;
    if (n >= N) return;

    const float HAMON = P[ 0*N+n], SCF   = P[ 1*N+n], PXTEMP= P[ 2*N+n];
    const float MFMAX = P[ 3*N+n], MFMIN = P[ 4*N+n], UADJ  = P[ 5*N+n];
    const float MBASE = P[ 6*N+n], TIPM  = P[ 7*N+n], PLWHC = P[ 8*N+n];
    const float NMF   = P[ 9*N+n], DAYGM = P[10*N+n];
    const float UZTWM = P[11*N+n], UZFWM = P[12*N+n], LZTWM = P[13*N+n];
    const float LZFPM = P[14*N+n], LZFSM = P[15*N+n], UZK   = P[16*N+n];
    const float LZPK  = P[17*N+n], LZSK  = P[18*N+n], ZPERC = P[19*N+n];
    const float REXP  = P[20*N+n], PFREE = P[21*N+n], PCTIM = P[22*N+n];
    const float ADIMP = P[23*N+n], SIDE  = P[25*N+n];
    const float UH_N  = P[28*N+n], UH_TAU= P[29*N+n];

    const float pa_fac = __expf(-elev_m[n] * (1.0f/8434.0f));
    const float tanlat = __tanf(lat_rad[n]);
    const float wA     = area_w[n];
    const int   bi     = basin_idx[n];

    float uh[UH_LEN]; float uhs = 0.0f;
    const float inv_tau = frcp(UH_TAU);
    #pragma unroll
    for (int l = 0; l < UH_LEN; ++l) {
        uh[l] = __expf((UH_N - 1.0f)*LOGT[l] - (float)(l+1)*inv_tau);
        uhs += uh[l];
    }
    float inv_uhs = frcp(uhs);
    #pragma unroll
    for (int l = 0; l < UH_LEN; ++l) uh[l] *= inv_uhs;

    const float dtq       = 1.0f / (float)N_INC;
    const float percm     = LZFPM*LZPK + LZFSM*LZSK;
    const float lz_max    = LZTWM + LZFPM + LZFSM;
    const float twm_sum   = UZTWM + LZTWM;
    const float inv_uztwm = frcp(UZTWM);
    const float inv_twm   = frcp(twm_sum);
    const float inv_uzfwm = frcp(UZFWM);
    const float inv_lzmax = frcp(lz_max);
    const float inv_side  = frcp(1.0f + SIDE);
    const float pinc_fac  = (1.0f - PCTIM - ADIMP)*dtq;
    const float mfa = 0.5f*(MFMAX + MFMIN), mfb = 0.5f*(MFMAX - MFMIN);

    float wi = 0.0f, wq = 0.0f, ati = 0.0f;
    float uztwc = 0.5f*UZTWM, uzfwc = 0.5f*UZFWM, lztwc = 0.5f*LZTWM;
    float lzfpc = 0.5f*LZFPM, lzfsc = 0.5f*LZFSM, adimc = 0.5f*twm_sum;
    float hist[UH_LEN-1];
    #pragma unroll
    for (int l = 0; l < UH_LEN-1; ++l) hist[l] = 0.0f;

    float* q_gauge = out;
    float* q_base  = out + (size_t)B*T;
    float* q_unit  = out + (size_t)2*B*T;

    for (int t = 0; t < T; ++t) {
        const float pr  = prcp[(size_t)n*T + t];
        const float ta  = tavg[(size_t)n*T + t];
        const int   dyi = doy [(size_t)n*T + t];

        float pet;
        if (PETPRE) {
            pet = petA[(size_t)n*T + t];
        } else {
            float dy = (float)dyi;
            float decl  = 0.4093f*__sinf(TWO_PI_365*dy - 1.405f);
            float cosw  = fminf(fmaxf(-tanlat*__tanf(decl), -0.9999f), 0.9999f);
            float daylen= acosf(cosw)*H24_PI;
            float esat  = 0.6108f*__expf(17.27f*ta*frcp(ta + 237.3f));
            pet = fmaxf(HAMON*29.8f*daylen*esat*frcp(ta + 273.2f), 0.0f);
        }

        // --- Snow17 ---
        bool is_snow = (ta <= PXTEMP);
        float ps    = is_snow ? pr*SCF : 0.0f;
        float prain = is_snow ? 0.0f   : pr;
        wi += ps;
        float mf = mfa + mfb*s366[dyi];
        ati += TIPM*(fminf(ta, 0.0f) - ati);
        float mros = UADJ*pa_fac*fmaxf(ta, 0.0f)*((!is_snow && wi > 0.0f) ? prain : 0.0f)*0.0125f;
        float melt = fminf(fmaxf(mf*fmaxf(ta - MBASE, 0.0f) + mros - NMF*fmaxf(-ati, 0.0f), 0.0f), wi);
        wi -= melt;
        float gm = fminf(DAYGM, wi);
        wi -= gm;
        float rop   = (wi > 0.0f) ? prain : 0.0f;
        float rfree = prain - rop;
        wq += melt + rop;
        float outq = fmaxf(wq - PLWHC*wi, 0.0f);
        wq -= outq;
        float eff = outq + gm + rfree;

        // --- SAC-SMA ---
        float e1 = fminf(pet*uztwc*inv_uztwm, uztwc);
        uztwc -= e1;
        float red = pet - e1;
        float e2 = fminf(red, uzfwc);
        uzfwc -= e2; red -= e2;
        float e3 = fminf(red*lztwc*inv_twm, lztwc);
        lztwc -= e3;
        float roimp  = eff*PCTIM;
        float padimp = eff*ADIMP;
        adimc += padimp;
        float ratio = fminf(fmaxf(adimc*inv_twm, 0.0f), 1.0f);
        float adsur = padimp*ratio*ratio;
        adimc = fminf(adimc - adsur, twm_sum);
        float surf = roimp + adsur;
        float base = 0.0f;
        float pinc = eff*pinc_fac;
        #pragma unroll
        for (int inc = 0; inc < N_INC; ++inc) {
            float bfp = lzfpc*LZPK*dtq;
            float bfs = lzfsc*LZSK*dtq;
            lzfpc -= bfp; lzfsc -= bfs;
            base += (bfp + bfs)*inv_side;
            float qif = uzfwc*UZK*dtq;
            uzfwc -= qif; surf += qif;
            float lz_def = (LZTWM - lztwc) + (LZFPM - lzfpc) + (LZFSM - lzfsc);
            float defr = fminf(fmaxf(lz_def*inv_lzmax, 1e-6f), 1.0f);
            float perc = percm*(1.0f + ZPERC*__expf(REXP*__logf(defr)))*dtq*uzfwc*inv_uzfwm;
            perc = fminf(fminf(perc, uzfwc), fmaxf(lz_def, 0.0f));
            uzfwc -= perc;
            float pfree = perc*PFREE;
            lztwc += perc - pfree;
            float ex = fmaxf(lztwc - LZTWM, 0.0f);
            lztwc -= ex; pfree += ex;
            float dp  = fmaxf(LZFPM - lzfpc, 0.0f);
            float dsx = fmaxf(LZFSM - lzfsc, 0.0f);
            float fr  = dp*frcp(fmaxf(dp + dsx, 1e-6f));
            lzfpc += pfree*fr;
            lzfsc += pfree*(1.0f - fr);
            float exq = fmaxf(lzfpc - LZFPM, 0.0f);
            lzfpc -= exq; lzfsc += exq;
            float exs = fmaxf(lzfsc - LZFSM, 0.0f);
            lzfsc -= exs; surf += exs;
            uztwc += pinc;
            float exu = fmaxf(uztwc - UZTWM, 0.0f);
            uztwc -= exu; uzfwc += exu;
            float exf = fmaxf(uzfwc - UZFWM, 0.0f);
            uzfwc -= exf; surf += exf;
        }

        // --- routing ---
        float qv = uh[0]*surf;
        #pragma unroll
        for (int l = 1; l < UH_LEN; ++l) qv = fmaf(uh[l], hist[l-1], qv);
        #pragma unroll
        for (int l = UH_LEN-2; l >= 1; --l) hist[l] = hist[l-1];
        hist[0] = surf;
        qv += base;

        q_unit[(size_t)n*T + t] = qv;
        atomicAdd(&q_gauge[(size_t)bi*T + t], qv*wA);
        atomicAdd(&q_base [(size_t)bi*T + t], base*wA);
    }
}

extern "C" void kernel_launch(void* const* d_in, const int* in_sizes, int n_in,
                              void* d_out, int out_size, void* d_ws, size_t ws_size,
                              hipStream_t stream) {
    const float* x_dyn    = (const float*)d_in[0];
    const float* x_static = (const float*)d_in[1];
    const float* prcp     = (const float*)d_in[2];
    const float* tavg     = (const float*)d_in[3];
    const int*   doy      = (const int*)  d_in[4];
    const float* elev_m   = (const float*)d_in[5];
    const float* lat_rad  = (const float*)d_in[6];
    const float* area_w   = (const float*)d_in[7];
    const int*   basin_ix = (const int*)  d_in[8];
    const float* Wih      = (const float*)d_in[10];
    const float* Whh      = (const float*)d_in[11];
    const float* b_lstm   = (const float*)d_in[12];
    const float* Ws       = (const float*)d_in[13];
    const float* bs       = (const float*)d_in[14];
    const float* Wout     = (const float*)d_in[15];
    const float* bout     = (const float*)d_in[16];

    const int N = in_sizes[7];
    const int T = in_sizes[2] / N;
    const int DSTAT = in_sizes[1] / N;
    const int NT = N * T;
    const int B = (out_size - NT) / (2 * T);

    float* params = (float*)d_ws;                       // [30][N]
    float* pet    = params + 30*(size_t)N;              // [N][T]
    const size_t need = (30*(size_t)N + (size_t)NT) * sizeof(float);
    const bool petpre = (ws_size >= need);
    float* out = (float*)d_out;

    const int zc = 2 * B * T;
    zero_kernel<<<(zc + 255)/256, 256, 0, stream>>>(out, zc);

    const int blocks_lstm = (N + 15) / 16;
    lstm_kernel<<<blocks_lstm, 256, 0, stream>>>(x_dyn, x_static, Wih, Whh, b_lstm,
                                                 Ws, bs, Wout, bout, params, N, T, DSTAT);

    if (petpre) {
        dim3 pg((T + 255)/256, N);
        pet_kernel<<<pg, 256, 0, stream>>>(tavg, doy, lat_rad, params, pet, N, T);
    }

    const int pblocks = (N + 63) / 64;
    if (petpre)
        physics_kernel<true ><<<pblocks, 64, 0, stream>>>(prcp, tavg, doy, elev_m, lat_rad,
                                                          area_w, basin_ix, params, pet,
                                                          out, N, T, B);
    else
        physics_kernel<false><<<pblocks, 64, 0, stream>>>(prcp, tavg, doy, elev_m, lat_rad,
                                                          area_w, basin_ix, params, pet,
                                                          out, N, T, B);
}

// Round 4
// 1362.138 us; speedup vs baseline: 2.6575x; 1.1057x over previous
//
#include <hip/hip_runtime.h>
#include <math.h>

#define HID 64
#define UH_LEN 15
#define N_INC 4

#define TWO_PI_365 0.0172142063f
#define TWO_PI_366 0.0171671554f
#define H24_PI     7.63943727f

typedef short short8 __attribute__((ext_vector_type(8)));
typedef float f32x4  __attribute__((ext_vector_type(4)));

__device__ __forceinline__ float frcp(float x){ return __builtin_amdgcn_rcpf(x); }
__device__ __forceinline__ float sigf(float x){ return frcp(1.0f + __expf(-x)); }
__device__ __forceinline__ float tanhfast(float x){ return 1.0f - 2.0f*frcp(__expf(2.0f*x)+1.0f); }

__device__ __forceinline__ unsigned short f2bf(float f){
    unsigned int u = __float_as_uint(f);
    u += 0x7FFF + ((u >> 16) & 1);
    return (unsigned short)(u >> 16);
}
__device__ __forceinline__ float bf2f(unsigned short h){
    return __uint_as_float(((unsigned int)h) << 16);
}

__device__ const float PLO[30] = {0.5f,0.7f,-2.0f,0.5f,0.05f,0.03f,0.0f,0.1f,0.02f,0.05f,0.0f,
                                  10.0f,5.0f,10.0f,10.0f,5.0f,0.1f,0.001f,0.01f,5.0f,1.0f,0.0f,
                                  0.0f,0.0f,0.0f,0.0f,0.0f,0.0f,1.0f,0.5f};
__device__ const float PHI[30] = {2.0f,1.4f,2.0f,2.0f,0.49f,0.19f,1.0f,1.0f,0.3f,0.5f,0.3f,
                                  300.0f,150.0f,500.0f,1000.0f,400.0f,0.75f,0.05f,0.35f,350.0f,5.0f,0.8f,
                                  0.1f,0.4f,0.2f,0.5f,0.4f,1.0f,6.0f,5.0f};
__device__ const float LOGT[15] = {0.0f,0.69314718f,1.09861229f,1.38629436f,1.60943791f,
                                   1.79175947f,1.94591015f,2.07944154f,2.19722458f,2.30258509f,
                                   2.39789527f,2.48490665f,2.56494936f,2.63905733f,2.70805020f};

__global__ void zero_kernel(float* __restrict__ p, int cnt){
    int i = blockIdx.x*256 + threadIdx.x;
    if (i < cnt) p[i] = 0.0f;
}

// ---------------------------------------------------------------------------
// MFMA LSTM (r3 structure). Change: x-part MFMA issued FIRST (no LDS dep) so
// ds_read latency for h-fragments hides under the matrix pipe.
// ---------------------------------------------------------------------------
__global__ __launch_bounds__(256, 1) void lstm_kernel(
    const float* __restrict__ x_dyn, const float* __restrict__ x_static,
    const float* __restrict__ Wih, const float* __restrict__ Whh,
    const float* __restrict__ b_lstm, const float* __restrict__ Ws,
    const float* __restrict__ bs, const float* __restrict__ Wout,
    const float* __restrict__ bout, float* __restrict__ params,
    int N, int T, int DSTAT)
{
    __shared__ unsigned short h_lds[2][16*64];
    __shared__ float s_sh[16*64];

    const int tid = threadIdx.x;
    const int wv  = tid >> 6;
    const int ln  = tid & 63;
    const int q   = ln >> 4;
    const int r16 = ln & 15;
    const int u0  = blockIdx.x * 16;

    short8 wf[4][3];
    float  bias[4];
    #pragma unroll
    for (int g = 0; g < 4; ++g) {
        const int n = 64*g + 16*wv + r16;
        bias[g] = b_lstm[n];
        #pragma unroll
        for (int kb = 0; kb < 3; ++kb) {
            short8 w;
            #pragma unroll
            for (int e = 0; e < 8; ++e) {
                int k = 32*kb + 8*q + e;
                float v = 0.0f;
                if (k < 64)      v = Whh[n*64 + k];
                else if (k < 72) v = Wih[n*8 + (k - 64)];
                w[e] = (short)f2bf(v);
            }
            wf[g][kb] = w;
        }
    }

    for (int i = tid; i < 2*16*64; i += 256) ((unsigned short*)h_lds)[i] = 0;
    __syncthreads();

    float c[4] = {0.f, 0.f, 0.f, 0.f};

    const int ux = min(u0 + r16, N-1);
    float xf[8];
    if (q == 0) {
        const float* p = x_dyn + ((size_t)ux * T) * 8;
        #pragma unroll
        for (int e = 0; e < 8; ++e) xf[e] = p[e];
    }

    const int jj   = 16*wv + r16;
    const int swz0 = (q       ^ (r16 & 7)) << 3;
    const int swz1 = ((q + 4) ^ (r16 & 7)) << 3;

    for (int t = 0; t < T; ++t) {
        short8 a2;
        #pragma unroll
        for (int e = 0; e < 8; ++e) a2[e] = (q == 0) ? (short)f2bf(xf[e]) : (short)0;

        const int rb = t & 1;
        short8 a0 = *(const short8*)&h_lds[rb][r16*64 + swz0];
        short8 a1 = *(const short8*)&h_lds[rb][r16*64 + swz1];

        if (q == 0 && t + 1 < T) {
            const float* p = x_dyn + ((size_t)ux * T + (t+1)) * 8;
            #pragma unroll
            for (int e = 0; e < 8; ++e) xf[e] = p[e];
        }

        f32x4 acc[4];
        #pragma unroll
        for (int g = 0; g < 4; ++g) {
            f32x4 a; a[0]=bias[g]; a[1]=bias[g]; a[2]=bias[g]; a[3]=bias[g];
            // x-part first: no dependency on the two ds_reads above
            a = __builtin_amdgcn_mfma_f32_16x16x32_bf16(a2, wf[g][2], a, 0, 0, 0);
            a = __builtin_amdgcn_mfma_f32_16x16x32_bf16(a0, wf[g][0], a, 0, 0, 0);
            a = __builtin_amdgcn_mfma_f32_16x16x32_bf16(a1, wf[g][1], a, 0, 0, 0);
            acc[g] = a;
        }

        const int wb = rb ^ 1;
        #pragma unroll
        for (int r = 0; r < 4; ++r) {
            float iv = sigf(acc[0][r]);
            float fv = sigf(acc[1][r]);
            float gv = tanhfast(acc[2][r]);
            float ov = sigf(acc[3][r]);
            c[r] = fv*c[r] + iv*gv;
            float hv = ov*tanhfast(c[r]);
            int u = 4*q + r;
            h_lds[wb][u*64 + (((jj>>3) ^ (u&7))<<3) + (jj&7)] = f2bf(hv);
        }
        __syncthreads();
    }

    const int fb = T & 1;
    for (int uu = 0; uu < 4; ++uu) {
        int ul = wv*4 + uu;
        int u  = min(u0 + ul, N-1);
        float a = bs[ln];
        for (int k = 0; k < DSTAT; ++k)
            a = fmaf(x_static[(size_t)u*DSTAT + k], Ws[ln*DSTAT + k], a);
        s_sh[ul*64 + ln] = tanhfast(a);
    }
    if (ln < 30) {
        for (int uu = 0; uu < 4; ++uu) {
            int ul = wv*4 + uu;
            int unit = u0 + ul;
            if (unit < N) {
                float raw = bout[ln];
                #pragma unroll 8
                for (int m = 0; m < 64; ++m) {
                    float hm = bf2f(h_lds[fb][ul*64 + (((m>>3) ^ (ul&7))<<3) + (m&7)]);
                    float sm = s_sh[ul*64 + m];
                    raw = fmaf(hm, Wout[ln*128 + m],      raw);
                    raw = fmaf(sm, Wout[ln*128 + 64 + m], raw);
                }
                float g = sigf(raw);
                params[ln*N + unit] = PLO[ln] + g*(PHI[ln] - PLO[ln]);
            }
        }
    }
}

// ---------------------------------------------------------------------------
// Physics: Snow17 + SAC-SMA serial chain ONLY.
// - inputs software-prefetched one step ahead (off the dep chain)
// - PET + melt-sine computed one step AHEAD in idle issue slots (no LUT,
//   no pet array, no LDS read in the chain)
// - SPLIT: store surf/base to ws; routing/atomics go to a parallel kernel.
//   !SPLIT fallback: inline routing + atomics (small-ws tier).
// ---------------------------------------------------------------------------
template<bool SPLIT>
__global__ __launch_bounds__(64, 1) void physics_kernel(
    const float* __restrict__ prcp, const float* __restrict__ tavg,
    const int*   __restrict__ doy,  const float* __restrict__ elev_m,
    const float* __restrict__ lat_rad, const float* __restrict__ area_w,
    const int*   __restrict__ basin_idx, const float* __restrict__ P,
    float* __restrict__ surfA, float* __restrict__ baseA,
    float* __restrict__ out, int N, int T, int B)
{
    int n = blockIdx.x*64 + threadIdx.x;
    if (n >= N) return;

    const float HAMON = P[ 0*N+n], SCF   = P[ 1*N+n], PXTEMP= P[ 2*N+n];
    const float MFMAX = P[ 3*N+n], MFMIN = P[ 4*N+n], UADJ  = P[ 5*N+n];
    const float MBASE = P[ 6*N+n], TIPM  = P[ 7*N+n], PLWHC = P[ 8*N+n];
    const float NMF   = P[ 9*N+n], DAYGM = P[10*N+n];
    const float UZTWM = P[11*N+n], UZFWM = P[12*N+n], LZTWM = P[13*N+n];
    const float LZFPM = P[14*N+n], LZFSM = P[15*N+n], UZK   = P[16*N+n];
    const float LZPK  = P[17*N+n], LZSK  = P[18*N+n], ZPERC = P[19*N+n];
    const float REXP  = P[20*N+n], PFREE = P[21*N+n], PCTIM = P[22*N+n];
    const float ADIMP = P[23*N+n], SIDE  = P[25*N+n];
    const float UH_N  = P[28*N+n], UH_TAU= P[29*N+n];

    const float pa_fac = __expf(-elev_m[n] * (1.0f/8434.0f));
    const float tanlat = __tanf(lat_rad[n]);
    const float wA     = area_w[n];
    const int   bi     = basin_idx[n];

    float uh[UH_LEN];
    float hist[UH_LEN-1];
    if (!SPLIT) {
        float uhs = 0.0f;
        const float inv_tau = frcp(UH_TAU);
        #pragma unroll
        for (int l = 0; l < UH_LEN; ++l) {
            uh[l] = __expf((UH_N - 1.0f)*LOGT[l] - (float)(l+1)*inv_tau);
            uhs += uh[l];
        }
        float inv_uhs = frcp(uhs);
        #pragma unroll
        for (int l = 0; l < UH_LEN; ++l) uh[l] *= inv_uhs;
        #pragma unroll
        for (int l = 0; l < UH_LEN-1; ++l) hist[l] = 0.0f;
    }

    const float dtq       = 1.0f / (float)N_INC;
    const float kp        = LZPK*dtq, ks = LZSK*dtq, ku = UZK*dtq;
    const float percm     = LZFPM*LZPK + LZFSM*LZSK;
    const float lz_max    = LZTWM + LZFPM + LZFSM;
    const float twm_sum   = UZTWM + LZTWM;
    const float inv_uztwm = frcp(UZTWM);
    const float inv_twm   = frcp(twm_sum);
    const float inv_uzfwm = frcp(UZFWM);
    const float inv_lzmax = frcp(lz_max);
    const float inv_side  = frcp(1.0f + SIDE);
    const float pinc_fac  = (1.0f - PCTIM - ADIMP)*dtq;
    const float pm        = percm*dtq*inv_uzfwm;
    const float mfa = 0.5f*(MFMAX + MFMIN), mfb = 0.5f*(MFMAX - MFMIN);

    float wi = 0.0f, wq = 0.0f, ati = 0.0f;
    float uztwc = 0.5f*UZTWM, uzfwc = 0.5f*UZFWM, lztwc = 0.5f*LZTWM;
    float lzfpc = 0.5f*LZFPM, lzfsc = 0.5f*LZFSM, adimc = 0.5f*twm_sum;

    float* q_gauge = out;
    float* q_base  = out + (size_t)B*T;
    float* q_unit  = out + (size_t)2*B*T;

    // ---- prime t=0 (pet/mf computed ahead of the chain) ----
    float pr_c = prcp[(size_t)n*T];
    float ta_c = tavg[(size_t)n*T];
    float dy_c = (float)doy[(size_t)n*T];
    float decl0  = 0.4093f*__sinf(TWO_PI_365*dy_c - 1.405f);
    float cosw0  = fminf(fmaxf(-tanlat*__tanf(decl0), -0.9999f), 0.9999f);
    float pet_c  = fmaxf(HAMON*29.8f*(acosf(cosw0)*H24_PI)
                         *0.6108f*__expf(17.27f*ta_c*frcp(ta_c + 237.3f))
                         *frcp(ta_c + 273.2f), 0.0f);
    float mf_c   = mfa + mfb*__sinf(TWO_PI_366*dy_c);

    for (int t = 0; t < T; ++t) {
        // issue t+1 loads immediately (latency hides under the chain)
        float pr_n = 0.f, ta_n = 0.f, dy_n = 0.f;
        if (t + 1 < T) {
            pr_n = prcp[(size_t)n*T + t + 1];
            ta_n = tavg[(size_t)n*T + t + 1];
            dy_n = (float)doy[(size_t)n*T + t + 1];
        }

        const float pr = pr_c, ta = ta_c, pet = pet_c, mf = mf_c;

        // --- Snow17 ---
        bool is_snow = (ta <= PXTEMP);
        float ps    = is_snow ? pr*SCF : 0.0f;
        float prain = is_snow ? 0.0f   : pr;
        wi += ps;
        ati += TIPM*(fminf(ta, 0.0f) - ati);
        float mros = UADJ*pa_fac*fmaxf(ta, 0.0f)*((!is_snow && wi > 0.0f) ? prain : 0.0f)*0.0125f;
        float melt = fminf(fmaxf(mf*fmaxf(ta - MBASE, 0.0f) + mros - NMF*fmaxf(-ati, 0.0f), 0.0f), wi);
        wi -= melt;
        float gm = fminf(DAYGM, wi);
        wi -= gm;
        float rop   = (wi > 0.0f) ? prain : 0.0f;
        float rfree = prain - rop;
        wq += melt + rop;
        float outq = fmaxf(wq - PLWHC*wi, 0.0f);
        wq -= outq;
        float eff = outq + gm + rfree;

        // --- SAC-SMA ---
        float e1 = fminf(pet*uztwc*inv_uztwm, uztwc);
        uztwc -= e1;
        float red = pet - e1;
        float e2 = fminf(red, uzfwc);
        uzfwc -= e2; red -= e2;
        float e3 = fminf(red*lztwc*inv_twm, lztwc);
        lztwc -= e3;
        float roimp  = eff*PCTIM;
        float padimp = eff*ADIMP;
        adimc += padimp;
        float ratio = fminf(fmaxf(adimc*inv_twm, 0.0f), 1.0f);
        float adsur = padimp*ratio*ratio;
        adimc = fminf(adimc - adsur, twm_sum);
        float surf = roimp + adsur;
        float base = 0.0f;
        float pinc = eff*pinc_fac;
        #pragma unroll
        for (int inc = 0; inc < N_INC; ++inc) {
            float bfp = lzfpc*kp;
            float bfs = lzfsc*ks;
            lzfpc -= bfp; lzfsc -= bfs;
            base += (bfp + bfs)*inv_side;
            float qif = uzfwc*ku;
            uzfwc -= qif; surf += qif;
            float lz_def = (LZTWM - lztwc) + (LZFPM - lzfpc) + (LZFSM - lzfsc);
            float defr = fminf(fmaxf(lz_def*inv_lzmax, 1e-6f), 1.0f);
            float perc = pm*fmaf(ZPERC, __expf(REXP*__logf(defr)), 1.0f)*uzfwc;
            perc = fminf(fminf(perc, uzfwc), fmaxf(lz_def, 0.0f));
            uzfwc -= perc;
            float pfree = perc*PFREE;
            lztwc += perc - pfree;
            float ex = fmaxf(lztwc - LZTWM, 0.0f);
            lztwc -= ex; pfree += ex;
            float dp  = fmaxf(LZFPM - lzfpc, 0.0f);
            float dsx = fmaxf(LZFSM - lzfsc, 0.0f);
            float fr  = dp*frcp(fmaxf(dp + dsx, 1e-6f));
            lzfpc += pfree*fr;
            lzfsc += pfree*(1.0f - fr);
            float exq = fmaxf(lzfpc - LZFPM, 0.0f);
            lzfpc -= exq; lzfsc += exq;
            float exs = fmaxf(lzfsc - LZFSM, 0.0f);
            lzfsc -= exs; surf += exs;
            uztwc += pinc;
            float exu = fmaxf(uztwc - UZTWM, 0.0f);
            uztwc -= exu; uzfwc += exu;
            float exf = fmaxf(uzfwc - UZFWM, 0.0f);
            uzfwc -= exf; surf += exf;
        }

        if (SPLIT) {
            surfA[(size_t)n*T + t] = surf;
            baseA[(size_t)n*T + t] = base;
        } else {
            float qv = uh[0]*surf;
            #pragma unroll
            for (int l = 1; l < UH_LEN; ++l) qv = fmaf(uh[l], hist[l-1], qv);
            #pragma unroll
            for (int l = UH_LEN-2; l >= 1; --l) hist[l] = hist[l-1];
            hist[0] = surf;
            qv += base;
            q_unit[(size_t)n*T + t] = qv;
            atomicAdd(&q_gauge[(size_t)bi*T + t], qv*wA);
            atomicAdd(&q_base [(size_t)bi*T + t], base*wA);
        }

        // --- ahead-compute pet/mf for t+1 (independent; fills stall slots) ---
        if (t + 1 < T) {
            float decl  = 0.4093f*__sinf(TWO_PI_365*dy_n - 1.405f);
            float cosw  = fminf(fmaxf(-tanlat*__tanf(decl), -0.9999f), 0.9999f);
            pet_c = fmaxf(HAMON*29.8f*(acosf(cosw)*H24_PI)
                          *0.6108f*__expf(17.27f*ta_n*frcp(ta_n + 237.3f))
                          *frcp(ta_n + 273.2f), 0.0f);
            mf_c  = mfa + mfb*__sinf(TWO_PI_366*dy_n);
            pr_c = pr_n; ta_c = ta_n;
        }
    }
}

// ---------------------------------------------------------------------------
// Routing + gauge segment-sum: fully parallel over (n, t).
// Block = 256 threads over t for one unit n; uh built once per block in LDS.
// ---------------------------------------------------------------------------
__global__ __launch_bounds__(256) void route_kernel(
    const float* __restrict__ surfA, const float* __restrict__ baseA,
    const float* __restrict__ P, const float* __restrict__ area_w,
    const int* __restrict__ basin_idx,
    float* __restrict__ out, int N, int T, int B)
{
    __shared__ float uh_sh[UH_LEN];
    __shared__ float wA_sh;
    __shared__ int   bi_sh;

    const int n = blockIdx.y;
    const int t = blockIdx.x*256 + threadIdx.x;

    if (threadIdx.x == 0) {
        float UH_N = P[28*N + n], UH_TAU = P[29*N + n];
        float inv_tau = frcp(UH_TAU);
        float tmp[UH_LEN], s = 0.f;
        #pragma unroll
        for (int l = 0; l < UH_LEN; ++l) {
            tmp[l] = __expf((UH_N - 1.0f)*LOGT[l] - (float)(l+1)*inv_tau);
            s += tmp[l];
        }
        float is = frcp(s);
        #pragma unroll
        for (int l = 0; l < UH_LEN; ++l) uh_sh[l] = tmp[l]*is;
        wA_sh = area_w[n];
        bi_sh = basin_idx[n];
    }
    __syncthreads();
    if (t >= T) return;

    const float base = baseA[(size_t)n*T + t];
    float acc = 0.f;
    #pragma unroll
    for (int l = 0; l < UH_LEN; ++l) {
        int tt = t - l;
        if (tt >= 0) acc = fmaf(uh_sh[l], surfA[(size_t)n*T + tt], acc);
    }
    const float qv = acc + base;

    float* q_gauge = out;
    float* q_base  = out + (size_t)B*T;
    float* q_unit  = out + (size_t)2*B*T;

    q_unit[(size_t)n*T + t] = qv;
    atomicAdd(&q_gauge[(size_t)bi_sh*T + t], qv*wA_sh);
    atomicAdd(&q_base [(size_t)bi_sh*T + t], base*wA_sh);
}

extern "C" void kernel_launch(void* const* d_in, const int* in_sizes, int n_in,
                              void* d_out, int out_size, void* d_ws, size_t ws_size,
                              hipStream_t stream) {
    const float* x_dyn    = (const float*)d_in[0];
    const float* x_static = (const float*)d_in[1];
    const float* prcp     = (const float*)d_in[2];
    const float* tavg     = (const float*)d_in[3];
    const int*   doy      = (const int*)  d_in[4];
    const float* elev_m   = (const float*)d_in[5];
    const float* lat_rad  = (const float*)d_in[6];
    const float* area_w   = (const float*)d_in[7];
    const int*   basin_ix = (const int*)  d_in[8];
    const float* Wih      = (const float*)d_in[10];
    const float* Whh      = (const float*)d_in[11];
    const float* b_lstm   = (const float*)d_in[12];
    const float* Ws       = (const float*)d_in[13];
    const float* bs       = (const float*)d_in[14];
    const float* Wout     = (const float*)d_in[15];
    const float* bout     = (const float*)d_in[16];

    const int N = in_sizes[7];
    const int T = in_sizes[2] / N;
    const int DSTAT = in_sizes[1] / N;
    const int NT = N * T;
    const int B = (out_size - NT) / (2 * T);

    float* params = (float*)d_ws;                       // [30][N]
    float* surfA  = params + 30*(size_t)N;              // [N][T]
    float* baseA  = surfA + (size_t)NT;                 // [N][T]
    const size_t need = (30*(size_t)N + 2*(size_t)NT) * sizeof(float);
    const bool split = (ws_size >= need);
    float* out = (float*)d_out;

    const int zc = 2 * B * T;
    zero_kernel<<<(zc + 255)/256, 256, 0, stream>>>(out, zc);

    const int blocks_lstm = (N + 15) / 16;
    lstm_kernel<<<blocks_lstm, 256, 0, stream>>>(x_dyn, x_static, Wih, Whh, b_lstm,
                                                 Ws, bs, Wout, bout, params, N, T, DSTAT);

    const int pblocks = (N + 63) / 64;
    if (split) {
        physics_kernel<true ><<<pblocks, 64, 0, stream>>>(prcp, tavg, doy, elev_m, lat_rad,
                                                          area_w, basin_ix, params,
                                                          surfA, baseA, out, N, T, B);
        dim3 rg((T + 255)/256, N);
        route_kernel<<<rg, 256, 0, stream>>>(surfA, baseA, params, area_w, basin_ix,
                                             out, N, T, B);
    } else {
        physics_kernel<false><<<pblocks, 64, 0, stream>>>(prcp, tavg, doy, elev_m, lat_rad,
                                                          area_w, basin_ix, params,
                                                          surfA, baseA, out, N, T, B);
    }
}